// Round 10
// baseline (214.764 us; speedup 1.0000x reference)
//
#include <hip/hip_runtime.h>
#include <hip/hip_fp16.h>
#include <hip/hip_cooperative_groups.h>
namespace cg = cooperative_groups;

#define BATCH 4096
#define IN_DIM 256
#define GRID_N 64
#define HID 128
constexpr float BN_EPS = 1e-5f;

// ---------------- workspace layout (bytes) ----------------
static const size_t O_MMP  = 0;        // 16 partials * 512 f = 32768 B
static const size_t O_ST1  = 32768;    // stats L1 (512 f)
static const size_t O_ST2  = 34816;    // stats L2 (256 f)
static const size_t O_ST3  = 35840;    // stats L3 (128 f)  [st1..st3 contiguous 896 f]
static const size_t O_STB  = 36864;    // packed fp16 table: 256*65*128 u32 = 8519680 B
static const size_t O_H    = O_STB + (size_t)256*65*128*4;
static const size_t O_A1   = O_H  + (size_t)4096*128*4;
static const size_t O_A2   = O_A1 + (size_t)4096*256*4;
static const size_t O_A3   = O_A2 + (size_t)4096*128*4;

// blocks 0..15: minmax partials (256 rows each); block 0 also zeros stats.
// blocks 16..271: packed prefix tables STb[i][K][h] = pack(fp16(S1), fp16(-S2)), i = bid-16
__global__ __launch_bounds__(256) void k_prep(const float* __restrict__ x, const float* __restrict__ fs,
                                              const float* __restrict__ grids,
                                              float* __restrict__ mmp, float* __restrict__ stz,
                                              unsigned* __restrict__ STb){
    const int tid = threadIdx.x;
    const int bid = blockIdx.x;
    if (bid < 16){
        // rows bid*256 .. +256, feature tid
        const float* xp = x + (size_t)bid*256*IN_DIM + tid;
        float mn = 1e30f, mx = -1e30f;
        #pragma unroll 8
        for (int r = 0; r < 256; ++r){
            float v = xp[(size_t)r*IN_DIM];
            mn = fminf(mn, v); mx = fmaxf(mx, v);
        }
        mmp[(size_t)bid*512 + tid]       = mn;
        mmp[(size_t)bid*512 + 256 + tid] = mx;
        if (bid == 0){
            for (int s = tid; s < 896; s += 256) stz[s] = 0.f;   // st1|st2|st3
        }
        return;
    }
    if (tid >= 128) return;
    const int i = bid - 16;             // 0..255
    const int h = tid;                  // 0..127
    const float* f0 = fs + ((size_t)(0*IN_DIM + i)*GRID_N)*HID + h;
    const float* f1 = fs + ((size_t)(1*IN_DIM + i)*GRID_N)*HID + h;
    const float* f2 = fs + ((size_t)(2*IN_DIM + i)*GRID_N)*HID + h;
    unsigned* st = STb + (size_t)i*65*HID + h;
    float acc1 = 0.f, acc2 = 0.f;
    st[0] = 0u;
    #pragma unroll 4
    for (int k = 0; k < 64; ++k){
        float fv = f0[(size_t)k*HID] + f1[(size_t)k*HID] + f2[(size_t)k*HID];
        float g  = grids[k];            // row 0 (identical across depth)
        acc1 += fv;
        acc2  = fmaf(g, fv, acc2);
        __half2 hh = __halves2half2(__float2half_rn(acc1), __float2half_rn(-acc2));
        st[(size_t)(k+1)*HID] = *reinterpret_cast<unsigned*>(&hh);
    }
}

// h[b,:] = sum_i ( z*S1[i,K0,:] - S2[i,K0,:] )  [fp16 packed table]
// 2 waves/block, one batch row per wave; lane l covers h = {2l, 2l+1} via uint2 (8B)
__global__ __launch_bounds__(128) void k_gather(const float* __restrict__ x, const float* __restrict__ mmp,
                                                const unsigned* __restrict__ STb, float* __restrict__ h){
    __shared__ float s_zmin[256], s_inv[256];
    __shared__ float2 pre[2][256];      // (z, byte-offset bitcast) per (row_local, i)
    const int tid = threadIdx.x;
    const int b0  = blockIdx.x * 2;

    // reduce 16 min/max partials (L2-hot)
    for (int f = tid; f < 256; f += 128){
        float mn = 1e30f, mx = -1e30f;
        #pragma unroll
        for (int p = 0; p < 16; ++p){
            mn = fminf(mn, mmp[(size_t)p*512 + f]);
            mx = fmaxf(mx, mmp[(size_t)p*512 + 256 + f]);
        }
        s_zmin[f] = mn;
        s_inv[f]  = 1.0f / (mx - mn + 1e-6f);
    }
    __syncthreads();

    // precompute z and table-row byte offsets (coalesced x reads)
    for (int idx = tid; idx < 2*256; idx += 128){
        int bl = idx >> 8, i = idx & 255;
        float z = (x[(size_t)(b0 + bl)*IN_DIM + i] - s_zmin[i]) * s_inv[i];
        int K0 = (int)(z * 63.0f) + 1;
        K0 = max(1, min(63, K0));
        unsigned off = ((unsigned)(i*65 + K0)) << 9;    // row stride = 128 u32 = 512 B
        pre[bl][i] = make_float2(z, __uint_as_float(off));
    }
    __syncthreads();

    const int w = tid >> 6;             // wave id = local row
    const int l = tid & 63;             // lane
    const char* base = (const char*)STb + (size_t)l * 8;
    float acc0 = 0.f, acc1 = 0.f;
    #pragma unroll 8
    for (int i = 0; i < 256; ++i){
        float2 p = pre[w][i];           // wave-uniform LDS read -> broadcast
        uint2 u = *reinterpret_cast<const uint2*>(base + __float_as_uint(p.y));
        float2 fa = __half22float2(*reinterpret_cast<__half2*>(&u.x));
        float2 fb = __half22float2(*reinterpret_cast<__half2*>(&u.y));
        acc0 += fmaf(p.x, fa.x, fa.y);  // h = 2l
        acc1 += fmaf(p.x, fb.x, fb.y);  // h = 2l+1
    }
    *reinterpret_cast<float2*>(&h[(size_t)(b0 + w)*HID + 2*l]) = make_float2(acc0, acc1);
}

// ---------------- fused MLP (cooperative, 256 blocks x 256 thr) ----------------
struct MlpSmem {
    float As[64][33];
    float Ws[32][64];
    float bnsc[256], bnsh[256];
    float red[16][16][8];
};

template<int BN_IN>
__device__ __forceinline__ void gemm_phase(MlpSmem& sm,
        const float* __restrict__ A, const float* __restrict__ W, const float* __restrict__ bias,
        const float* __restrict__ instats, const float* __restrict__ gam, const float* __restrict__ bet,
        float* __restrict__ C, float* __restrict__ ostats, int K, int N){
    const int tid = threadIdx.x;
    if (BN_IN){
        for (int k = tid; k < K; k += 256){
            float m  = instats[k]     * (1.0f/BATCH);
            float v  = instats[K + k] * (1.0f/BATCH) - m*m;
            float rs = rsqrtf(v + BN_EPS);
            float s  = gam[k]*rs;
            sm.bnsc[k] = s;
            sm.bnsh[k] = fmaf(-m, s, bet[k]);
        }
    }
    __syncthreads();

    const int nt = tid & 15;
    const int bt = tid >> 4;
    const int ntN = N >> 6;
    const int ntiles = (BATCH >> 6) * ntN;
    for (int tile = blockIdx.x; tile < ntiles; tile += gridDim.x){
        const int n0 = (tile % ntN) << 6;
        const int b0 = (tile / ntN) << 6;
        float acc[4][4];
        #pragma unroll
        for (int r = 0; r < 4; ++r)
            #pragma unroll
            for (int j = 0; j < 4; ++j) acc[r][j] = 0.f;

        for (int kc = 0; kc < K; kc += 32){
            #pragma unroll
            for (int idx = tid; idx < 64*32; idx += 256){
                int r = idx >> 5, k = idx & 31;
                float a = A[(size_t)(b0 + r)*K + kc + k];
                if (BN_IN) a = fmaf(a, sm.bnsc[kc + k], sm.bnsh[kc + k]);
                sm.As[r][k] = a;
            }
            #pragma unroll
            for (int idx = tid; idx < 32*64; idx += 256){
                int k = idx >> 6, n = idx & 63;
                sm.Ws[k][n] = W[(size_t)(kc + k)*N + n0 + n];
            }
            __syncthreads();
            #pragma unroll
            for (int k = 0; k < 32; ++k){
                float4 w = *reinterpret_cast<const float4*>(&sm.Ws[k][nt*4]);
                float a0 = sm.As[bt*4+0][k], a1 = sm.As[bt*4+1][k], a2 = sm.As[bt*4+2][k], a3 = sm.As[bt*4+3][k];
                acc[0][0] = fmaf(a0, w.x, acc[0][0]); acc[0][1] = fmaf(a0, w.y, acc[0][1]);
                acc[0][2] = fmaf(a0, w.z, acc[0][2]); acc[0][3] = fmaf(a0, w.w, acc[0][3]);
                acc[1][0] = fmaf(a1, w.x, acc[1][0]); acc[1][1] = fmaf(a1, w.y, acc[1][1]);
                acc[1][2] = fmaf(a1, w.z, acc[1][2]); acc[1][3] = fmaf(a1, w.w, acc[1][3]);
                acc[2][0] = fmaf(a2, w.x, acc[2][0]); acc[2][1] = fmaf(a2, w.y, acc[2][1]);
                acc[2][2] = fmaf(a2, w.z, acc[2][2]); acc[2][3] = fmaf(a2, w.w, acc[2][3]);
                acc[3][0] = fmaf(a3, w.x, acc[3][0]); acc[3][1] = fmaf(a3, w.y, acc[3][1]);
                acc[3][2] = fmaf(a3, w.z, acc[3][2]); acc[3][3] = fmaf(a3, w.w, acc[3][3]);
            }
            __syncthreads();
        }

        float bs[4];
        #pragma unroll
        for (int j = 0; j < 4; ++j) bs[j] = bias[n0 + nt*4 + j];
        float lsum[4] = {0,0,0,0}, lsq[4] = {0,0,0,0};
        #pragma unroll
        for (int r = 0; r < 4; ++r){
            int brow = b0 + bt*4 + r;
            float vv[4];
            #pragma unroll
            for (int j = 0; j < 4; ++j){
                float v1 = acc[r][j] + bs[j];
                v1 = fmaxf(v1, 0.f);
                vv[j] = v1;
                lsum[j] += v1;
                lsq[j]  = fmaf(v1, v1, lsq[j]);
            }
            *reinterpret_cast<float4*>(&C[(size_t)brow*N + n0 + nt*4]) =
                make_float4(vv[0], vv[1], vv[2], vv[3]);
        }
        #pragma unroll
        for (int j = 0; j < 4; ++j){ sm.red[bt][nt][j] = lsum[j]; sm.red[bt][nt][4+j] = lsq[j]; }
        __syncthreads();
        for (int s = 8; s > 0; s >>= 1){
            if (bt < s){
                #pragma unroll
                for (int f = 0; f < 8; ++f) sm.red[bt][nt][f] += sm.red[bt+s][nt][f];
            }
            __syncthreads();
        }
        if (bt == 0){
            #pragma unroll
            for (int j = 0; j < 4; ++j){
                atomicAdd(&ostats[n0 + nt*4 + j],     sm.red[0][nt][j]);
                atomicAdd(&ostats[N + n0 + nt*4 + j], sm.red[0][nt][4+j]);
            }
        }
        __syncthreads();
    }
}

__global__ __launch_bounds__(256) void k_mlp(const float* __restrict__ A0,
        const float* __restrict__ w1, const float* __restrict__ b1,
        const float* __restrict__ gm1, const float* __restrict__ bt1,
        const float* __restrict__ w2, const float* __restrict__ b2,
        const float* __restrict__ gm2, const float* __restrict__ bt2,
        const float* __restrict__ w3, const float* __restrict__ b3,
        const float* __restrict__ gm3, const float* __restrict__ bt3,
        const float* __restrict__ w4, const float* __restrict__ b4,
        float* __restrict__ A1, float* __restrict__ A2, float* __restrict__ A3,
        float* __restrict__ s1, float* __restrict__ s2, float* __restrict__ s3,
        float* __restrict__ out){
    __shared__ MlpSmem sm;
    cg::grid_group grid = cg::this_grid();

    gemm_phase<0>(sm, A0, w1, b1, nullptr, nullptr, nullptr, A1, s1, 128, 256);
    grid.sync();
    gemm_phase<1>(sm, A1, w2, b2, s1, gm1, bt1, A2, s2, 256, 128);
    grid.sync();
    gemm_phase<1>(sm, A2, w3, b3, s2, gm2, bt2, A3, s3, 128, 64);
    grid.sync();

    // final: out = BN(A3) @ w4 + b4
    const int t = threadIdx.x;
    if (t < 64){
        float m  = s3[t]      * (1.0f/BATCH);
        float v  = s3[64 + t] * (1.0f/BATCH) - m*m;
        float rs = rsqrtf(v + BN_EPS);
        float s  = gm3[t]*rs;
        sm.bnsc[t] = s * w4[t];
        sm.bnsh[t] = fmaf(-m, s, bt3[t]) * w4[t];
    }
    __syncthreads();
    for (int row = blockIdx.x*256 + t; row < BATCH; row += gridDim.x*256){
        const float* a = A3 + (size_t)row*64;
        float acc = b4[0];
        #pragma unroll
        for (int k = 0; k < 64; ++k){
            acc = fmaf(a[k], sm.bnsc[k], acc);
            acc += sm.bnsh[k];
        }
        out[row] = acc;
    }
}

extern "C" void kernel_launch(void* const* d_in, const int* in_sizes, int n_in,
                              void* d_out, int out_size, void* d_ws, size_t ws_size,
                              hipStream_t stream){
    const float* x     = (const float*)d_in[0];
    const float* fs    = (const float*)d_in[1];
    const float* grids = (const float*)d_in[2];
    const float* w1 = (const float*)d_in[3];  const float* b1 = (const float*)d_in[4];
    const float* g1 = (const float*)d_in[5];  const float* be1= (const float*)d_in[6];
    const float* w2 = (const float*)d_in[7];  const float* b2 = (const float*)d_in[8];
    const float* g2 = (const float*)d_in[9];  const float* be2= (const float*)d_in[10];
    const float* w3 = (const float*)d_in[11]; const float* b3 = (const float*)d_in[12];
    const float* g3 = (const float*)d_in[13]; const float* be3= (const float*)d_in[14];
    const float* w4 = (const float*)d_in[15]; const float* b4 = (const float*)d_in[16];
    float* out = (float*)d_out;

    char* ws = (char*)d_ws;
    float* mmp    = (float*)(ws + O_MMP);
    float* st1    = (float*)(ws + O_ST1);
    float* st2    = (float*)(ws + O_ST2);
    float* st3    = (float*)(ws + O_ST3);
    unsigned* STb = (unsigned*)(ws + O_STB);
    float* h      = (float*)(ws + O_H);
    float* A1     = (float*)(ws + O_A1);
    float* A2     = (float*)(ws + O_A2);
    float* A3     = (float*)(ws + O_A3);

    k_prep<<<272, 256, 0, stream>>>(x, fs, grids, mmp, st1, STb);
    k_gather<<<2048, 128, 0, stream>>>(x, mmp, STb, h);

    void* margs[] = {
        (void*)&h,
        (void*)&w1, (void*)&b1, (void*)&g1, (void*)&be1,
        (void*)&w2, (void*)&b2, (void*)&g2, (void*)&be2,
        (void*)&w3, (void*)&b3, (void*)&g3, (void*)&be3,
        (void*)&w4, (void*)&b4,
        (void*)&A1, (void*)&A2, (void*)&A3,
        (void*)&st1, (void*)&st2, (void*)&st3,
        (void*)&out
    };
    hipLaunchCooperativeKernel((const void*)k_mlp, dim3(256), dim3(256), margs, 0, stream);
}

// Round 11
// 146.908 us; speedup vs baseline: 1.4619x; 1.4619x over previous
//
#include <hip/hip_runtime.h>
#include <hip/hip_fp16.h>

#define BATCH 4096
#define IN_DIM 256
#define GRID_N 64
#define HID 128
constexpr float BN_EPS = 1e-5f;

// ---------------- workspace layout (bytes) ----------------
static const size_t O_MMP  = 0;        // 16 partials * 512 f = 32768 B
static const size_t O_ST1  = 32768;    // stats L1 (512 f)
static const size_t O_ST2  = 34816;    // stats L2 (256 f)
static const size_t O_ST3  = 35840;    // stats L3 (128 f)  [st1..st3 contiguous 896 f]
static const size_t O_STB  = 36864;    // packed fp16 table: 256*65*128 u32 = 8519680 B
static const size_t O_H    = O_STB + (size_t)256*65*128*4;
static const size_t O_A1   = O_H  + (size_t)4096*128*4;
static const size_t O_A2   = O_A1 + (size_t)4096*256*4;
static const size_t O_A3   = O_A2 + (size_t)4096*128*4;

// blocks 0..15: minmax partials (256 rows each); block 0 also zeros stats.
// blocks 16..271: packed prefix tables STb[i][K][h] = pack(fp16(S1), fp16(-S2)), i = bid-16
__global__ __launch_bounds__(256) void k_prep(const float* __restrict__ x, const float* __restrict__ fs,
                                              const float* __restrict__ grids,
                                              float* __restrict__ mmp, float* __restrict__ stz,
                                              unsigned* __restrict__ STb){
    const int tid = threadIdx.x;
    const int bid = blockIdx.x;
    if (bid < 16){
        const float* xp = x + (size_t)bid*256*IN_DIM + tid;
        float mn = 1e30f, mx = -1e30f;
        #pragma unroll 8
        for (int r = 0; r < 256; ++r){
            float v = xp[(size_t)r*IN_DIM];
            mn = fminf(mn, v); mx = fmaxf(mx, v);
        }
        mmp[(size_t)bid*512 + tid]       = mn;
        mmp[(size_t)bid*512 + 256 + tid] = mx;
        if (bid == 0){
            for (int s = tid; s < 896; s += 256) stz[s] = 0.f;   // st1|st2|st3
        }
        return;
    }
    if (tid >= 128) return;
    const int i = bid - 16;             // 0..255
    const int h = tid;                  // 0..127
    const float* f0 = fs + ((size_t)(0*IN_DIM + i)*GRID_N)*HID + h;
    const float* f1 = fs + ((size_t)(1*IN_DIM + i)*GRID_N)*HID + h;
    const float* f2 = fs + ((size_t)(2*IN_DIM + i)*GRID_N)*HID + h;
    unsigned* st = STb + (size_t)i*65*HID + h;
    float acc1 = 0.f, acc2 = 0.f;
    st[0] = 0u;
    #pragma unroll 4
    for (int k = 0; k < 64; ++k){
        float fv = f0[(size_t)k*HID] + f1[(size_t)k*HID] + f2[(size_t)k*HID];
        float g  = grids[k];            // row 0 (identical across depth)
        acc1 += fv;
        acc2  = fmaf(g, fv, acc2);
        __half2 hh = __halves2half2(__float2half_rn(acc1), __float2half_rn(-acc2));
        st[(size_t)(k+1)*HID] = *reinterpret_cast<unsigned*>(&hh);
    }
}

// h[b,:] = sum_i ( z*S1[i,K0,:] - S2[i,K0,:] )  [fp16 packed table]
// 2 waves/block, one batch row per wave; lane l covers h = {2l, 2l+1} via uint2 (8B)
__global__ __launch_bounds__(128) void k_gather(const float* __restrict__ x, const float* __restrict__ mmp,
                                                const unsigned* __restrict__ STb, float* __restrict__ h){
    __shared__ float s_zmin[256], s_inv[256];
    __shared__ float2 pre[2][256];      // (z, byte-offset bitcast) per (row_local, i)
    const int tid = threadIdx.x;
    const int b0  = blockIdx.x * 2;

    // reduce 16 min/max partials (L2-hot)
    for (int f = tid; f < 256; f += 128){
        float mn = 1e30f, mx = -1e30f;
        #pragma unroll
        for (int p = 0; p < 16; ++p){
            mn = fminf(mn, mmp[(size_t)p*512 + f]);
            mx = fmaxf(mx, mmp[(size_t)p*512 + 256 + f]);
        }
        s_zmin[f] = mn;
        s_inv[f]  = 1.0f / (mx - mn + 1e-6f);
    }
    __syncthreads();

    // precompute z and table-row byte offsets (coalesced x reads)
    for (int idx = tid; idx < 2*256; idx += 128){
        int bl = idx >> 8, i = idx & 255;
        float z = (x[(size_t)(b0 + bl)*IN_DIM + i] - s_zmin[i]) * s_inv[i];
        int K0 = (int)(z * 63.0f) + 1;
        K0 = max(1, min(63, K0));
        unsigned off = ((unsigned)(i*65 + K0)) << 9;    // row stride = 128 u32 = 512 B
        pre[bl][i] = make_float2(z, __uint_as_float(off));
    }
    __syncthreads();

    const int w = tid >> 6;             // wave id = local row
    const int l = tid & 63;             // lane
    const char* base = (const char*)STb + (size_t)l * 8;
    float acc0 = 0.f, acc1 = 0.f;
    #pragma unroll 8
    for (int i = 0; i < 256; ++i){
        float2 p = pre[w][i];           // wave-uniform LDS read -> broadcast
        uint2 u = *reinterpret_cast<const uint2*>(base + __float_as_uint(p.y));
        float2 fa = __half22float2(*reinterpret_cast<__half2*>(&u.x));
        float2 fb = __half22float2(*reinterpret_cast<__half2*>(&u.y));
        acc0 += fmaf(p.x, fa.x, fa.y);  // h = 2l
        acc1 += fmaf(p.x, fb.x, fb.y);  // h = 2l+1
    }
    *reinterpret_cast<float2*>(&h[(size_t)(b0 + w)*HID + 2*l]) = make_float2(acc0, acc1);
}

// fp32 GEMM: C = relu(bn?(A) @ W + bias) + per-col sum/sumsq atomics
// tile 32x64 (BM=32, BN=64), KC=32, 256 threads, micro-tile 2x4 -> 2+ blocks/CU
// grid: (N/64, BATCH/32); one tile per block
template<int BN_IN>
__global__ __launch_bounds__(256) void k_gemm(const float* __restrict__ A, const float* __restrict__ W,
                                              const float* __restrict__ bias,
                                              const float* __restrict__ instats,
                                              const float* __restrict__ gam, const float* __restrict__ bet,
                                              float* __restrict__ C, float* __restrict__ ostats,
                                              int K, int N){
    __shared__ float As[32][33];
    __shared__ float Ws[32][64];
    __shared__ float bnsc[256], bnsh[256];
    __shared__ float red[16][16][8];

    const int tid = threadIdx.x;
    const int n0  = blockIdx.x * 64;
    const int b0  = blockIdx.y * 32;

    if (BN_IN){
        for (int k = tid; k < K; k += 256){
            float m  = instats[k]     * (1.0f/BATCH);
            float v  = instats[K + k] * (1.0f/BATCH) - m*m;
            float rs = rsqrtf(v + BN_EPS);
            float s  = gam[k]*rs;
            bnsc[k] = s;
            bnsh[k] = fmaf(-m, s, bet[k]);
        }
        __syncthreads();
    }

    const int nt = tid & 15;            // 16 col-groups * 4 cols
    const int bt = tid >> 4;            // 16 row-groups * 2 rows
    float acc[2][4];
    #pragma unroll
    for (int r = 0; r < 2; ++r)
        #pragma unroll
        for (int j = 0; j < 4; ++j) acc[r][j] = 0.f;

    for (int kc = 0; kc < K; kc += 32){
        #pragma unroll
        for (int idx = tid; idx < 32*32; idx += 256){
            int r = idx >> 5, k = idx & 31;
            float a = A[(size_t)(b0 + r)*K + kc + k];
            if (BN_IN) a = fmaf(a, bnsc[kc + k], bnsh[kc + k]);
            As[r][k] = a;
        }
        #pragma unroll
        for (int idx = tid; idx < 32*64; idx += 256){
            int k = idx >> 6, n = idx & 63;
            Ws[k][n] = W[(size_t)(kc + k)*N + n0 + n];
        }
        __syncthreads();
        #pragma unroll
        for (int k = 0; k < 32; ++k){
            float4 w = *reinterpret_cast<const float4*>(&Ws[k][nt*4]);
            float a0 = As[bt*2+0][k], a1 = As[bt*2+1][k];
            acc[0][0] = fmaf(a0, w.x, acc[0][0]); acc[0][1] = fmaf(a0, w.y, acc[0][1]);
            acc[0][2] = fmaf(a0, w.z, acc[0][2]); acc[0][3] = fmaf(a0, w.w, acc[0][3]);
            acc[1][0] = fmaf(a1, w.x, acc[1][0]); acc[1][1] = fmaf(a1, w.y, acc[1][1]);
            acc[1][2] = fmaf(a1, w.z, acc[1][2]); acc[1][3] = fmaf(a1, w.w, acc[1][3]);
        }
        __syncthreads();
    }

    float bs[4];
    #pragma unroll
    for (int j = 0; j < 4; ++j) bs[j] = bias[n0 + nt*4 + j];
    float lsum[4] = {0,0,0,0}, lsq[4] = {0,0,0,0};
    #pragma unroll
    for (int r = 0; r < 2; ++r){
        int brow = b0 + bt*2 + r;
        float vv[4];
        #pragma unroll
        for (int j = 0; j < 4; ++j){
            float v1 = acc[r][j] + bs[j];
            v1 = fmaxf(v1, 0.f);
            vv[j] = v1;
            lsum[j] += v1;
            lsq[j]  = fmaf(v1, v1, lsq[j]);
        }
        *reinterpret_cast<float4*>(&C[(size_t)brow*N + n0 + nt*4]) =
            make_float4(vv[0], vv[1], vv[2], vv[3]);
    }
    #pragma unroll
    for (int j = 0; j < 4; ++j){ red[bt][nt][j] = lsum[j]; red[bt][nt][4+j] = lsq[j]; }
    __syncthreads();
    for (int s = 8; s > 0; s >>= 1){
        if (bt < s){
            #pragma unroll
            for (int f = 0; f < 8; ++f) red[bt][nt][f] += red[bt+s][nt][f];
        }
        __syncthreads();
    }
    if (bt == 0){
        #pragma unroll
        for (int j = 0; j < 4; ++j){
            atomicAdd(&ostats[n0 + nt*4 + j],     red[0][nt][j]);
            atomicAdd(&ostats[N + n0 + nt*4 + j], red[0][nt][4+j]);
        }
    }
}

// out = BN(A3) @ w4 + b4
__global__ __launch_bounds__(256) void k_final(const float* __restrict__ A3, const float* __restrict__ st3,
                                               const float* __restrict__ g3, const float* __restrict__ be3,
                                               const float* __restrict__ w4, const float* __restrict__ b4,
                                               float* __restrict__ out){
    __shared__ float sc[64], sh[64];
    int t = threadIdx.x;
    if (t < 64){
        float m  = st3[t]      * (1.0f/BATCH);
        float v  = st3[64 + t] * (1.0f/BATCH) - m*m;
        float rs = rsqrtf(v + BN_EPS);
        float s  = g3[t]*rs;
        sc[t] = s * w4[t];
        sh[t] = fmaf(-m, s, be3[t]) * w4[t];
    }
    __syncthreads();
    int row = blockIdx.x*256 + t;
    const float* a = A3 + (size_t)row*64;
    float acc = b4[0];
    #pragma unroll
    for (int k = 0; k < 64; ++k){
        acc = fmaf(a[k], sc[k], acc);
        acc += sh[k];
    }
    out[row] = acc;
}

extern "C" void kernel_launch(void* const* d_in, const int* in_sizes, int n_in,
                              void* d_out, int out_size, void* d_ws, size_t ws_size,
                              hipStream_t stream){
    const float* x     = (const float*)d_in[0];
    const float* fs    = (const float*)d_in[1];
    const float* grids = (const float*)d_in[2];
    const float* w1 = (const float*)d_in[3];  const float* b1 = (const float*)d_in[4];
    const float* g1 = (const float*)d_in[5];  const float* be1= (const float*)d_in[6];
    const float* w2 = (const float*)d_in[7];  const float* b2 = (const float*)d_in[8];
    const float* g2 = (const float*)d_in[9];  const float* be2= (const float*)d_in[10];
    const float* w3 = (const float*)d_in[11]; const float* b3 = (const float*)d_in[12];
    const float* g3 = (const float*)d_in[13]; const float* be3= (const float*)d_in[14];
    const float* w4 = (const float*)d_in[15]; const float* b4 = (const float*)d_in[16];
    float* out = (float*)d_out;

    char* ws = (char*)d_ws;
    float* mmp    = (float*)(ws + O_MMP);
    float* st1    = (float*)(ws + O_ST1);
    float* st2    = (float*)(ws + O_ST2);
    float* st3    = (float*)(ws + O_ST3);
    unsigned* STb = (unsigned*)(ws + O_STB);
    float* h      = (float*)(ws + O_H);
    float* A1     = (float*)(ws + O_A1);
    float* A2     = (float*)(ws + O_A2);
    float* A3     = (float*)(ws + O_A3);

    k_prep<<<272, 256, 0, stream>>>(x, fs, grids, mmp, st1, STb);
    k_gather<<<2048, 128, 0, stream>>>(x, mmp, STb, h);
    k_gemm<0><<<dim3(4, 128), 256, 0, stream>>>(h,  w1, b1, nullptr, nullptr, nullptr, A1, st1, 128, 256);
    k_gemm<1><<<dim3(2, 128), 256, 0, stream>>>(A1, w2, b2, st1, g1, be1,            A2, st2, 256, 128);
    k_gemm<1><<<dim3(1, 128), 256, 0, stream>>>(A2, w3, b3, st2, g2, be2,            A3, st3, 128, 64);
    k_final<<<16, 256, 0, stream>>>(A3, st3, g3, be3, w4, b4, out);
}

// Round 12
// 140.497 us; speedup vs baseline: 1.5286x; 1.0456x over previous
//
#include <hip/hip_runtime.h>
#include <hip/hip_fp16.h>

#define BATCH 4096
#define IN_DIM 256
#define GRID_N 64
#define HID 128
#define GEMM_GB 128            // b-blocks per layer (BATCH/32)
constexpr float BN_EPS = 1e-5f;

// ---------------- workspace layout (bytes) ----------------
static const size_t O_MMP  = 0;                      // 16 partials * 512 f = 32768 B
static const size_t O_P1   = 32768;                  // stats partials L1: 128*512 f = 256 KB
static const size_t O_P2   = O_P1 + 262144;          // 128*256 f = 128 KB
static const size_t O_P3   = O_P2 + 131072;          // 128*128 f = 64 KB
static const size_t O_STB  = O_P3 + 65536;           // packed fp16 table: 256*65*128 u32
static const size_t O_H    = O_STB + (size_t)256*65*128*4;
static const size_t O_A1   = O_H  + (size_t)4096*128*4;
static const size_t O_A2   = O_A1 + (size_t)4096*256*4;
static const size_t O_A3   = O_A2 + (size_t)4096*128*4;

// blocks 0..15: minmax partials (256 rows each).
// blocks 16..271: packed prefix tables STb[i][K][h] = pack(fp16(S1), fp16(-S2)), i = bid-16
__global__ __launch_bounds__(256) void k_prep(const float* __restrict__ x, const float* __restrict__ fs,
                                              const float* __restrict__ grids,
                                              float* __restrict__ mmp, unsigned* __restrict__ STb){
    const int tid = threadIdx.x;
    const int bid = blockIdx.x;
    if (bid < 16){
        const float* xp = x + (size_t)bid*256*IN_DIM + tid;
        float mn = 1e30f, mx = -1e30f;
        #pragma unroll 8
        for (int r = 0; r < 256; ++r){
            float v = xp[(size_t)r*IN_DIM];
            mn = fminf(mn, v); mx = fmaxf(mx, v);
        }
        mmp[(size_t)bid*512 + tid]       = mn;
        mmp[(size_t)bid*512 + 256 + tid] = mx;
        return;
    }
    if (tid >= 128) return;
    const int i = bid - 16;             // 0..255
    const int h = tid;                  // 0..127
    const float* f0 = fs + ((size_t)(0*IN_DIM + i)*GRID_N)*HID + h;
    const float* f1 = fs + ((size_t)(1*IN_DIM + i)*GRID_N)*HID + h;
    const float* f2 = fs + ((size_t)(2*IN_DIM + i)*GRID_N)*HID + h;
    unsigned* st = STb + (size_t)i*65*HID + h;
    float acc1 = 0.f, acc2 = 0.f;
    st[0] = 0u;
    #pragma unroll 4
    for (int k = 0; k < 64; ++k){
        float fv = f0[(size_t)k*HID] + f1[(size_t)k*HID] + f2[(size_t)k*HID];
        float g  = grids[k];            // row 0 (identical across depth)
        acc1 += fv;
        acc2  = fmaf(g, fv, acc2);
        __half2 hh = __halves2half2(__float2half_rn(acc1), __float2half_rn(-acc2));
        st[(size_t)(k+1)*HID] = *reinterpret_cast<unsigned*>(&hh);
    }
}

// h[b,:] = sum_i ( z*S1[i,K0,:] - S2[i,K0,:] )  [fp16 packed table]
// 2 waves/block, one batch row per wave; lane l covers h = {2l, 2l+1} via uint2 (8B)
__global__ __launch_bounds__(128) void k_gather(const float* __restrict__ x, const float* __restrict__ mmp,
                                                const unsigned* __restrict__ STb, float* __restrict__ h){
    __shared__ float s_zmin[256], s_inv[256];
    __shared__ float2 pre[2][256];      // (z, byte-offset bitcast) per (row_local, i)
    const int tid = threadIdx.x;
    const int b0  = blockIdx.x * 2;

    // reduce 16 min/max partials (L2-hot)
    for (int f = tid; f < 256; f += 128){
        float mn = 1e30f, mx = -1e30f;
        #pragma unroll
        for (int p = 0; p < 16; ++p){
            mn = fminf(mn, mmp[(size_t)p*512 + f]);
            mx = fmaxf(mx, mmp[(size_t)p*512 + 256 + f]);
        }
        s_zmin[f] = mn;
        s_inv[f]  = 1.0f / (mx - mn + 1e-6f);
    }
    __syncthreads();

    // precompute z and table-row byte offsets (coalesced x reads)
    for (int idx = tid; idx < 2*256; idx += 128){
        int bl = idx >> 8, i = idx & 255;
        float z = (x[(size_t)(b0 + bl)*IN_DIM + i] - s_zmin[i]) * s_inv[i];
        int K0 = (int)(z * 63.0f) + 1;
        K0 = max(1, min(63, K0));
        unsigned off = ((unsigned)(i*65 + K0)) << 9;    // row stride = 128 u32 = 512 B
        pre[bl][i] = make_float2(z, __uint_as_float(off));
    }
    __syncthreads();

    const int w = tid >> 6;             // wave id = local row
    const int l = tid & 63;             // lane
    const char* base = (const char*)STb + (size_t)l * 8;
    float acc0 = 0.f, acc1 = 0.f;
    #pragma unroll 8
    for (int i = 0; i < 256; ++i){
        float2 p = pre[w][i];           // wave-uniform LDS read -> broadcast
        uint2 u = *reinterpret_cast<const uint2*>(base + __float_as_uint(p.y));
        float2 fa = __half22float2(*reinterpret_cast<__half2*>(&u.x));
        float2 fb = __half22float2(*reinterpret_cast<__half2*>(&u.y));
        acc0 += fmaf(p.x, fa.x, fa.y);  // h = 2l
        acc1 += fmaf(p.x, fb.x, fb.y);  // h = 2l+1
    }
    *reinterpret_cast<float2*>(&h[(size_t)(b0 + w)*HID + 2*l]) = make_float2(acc0, acc1);
}

// fp32 GEMM: C = relu(bn?(A) @ W + bias); per-column stats stored as PER-BLOCK
// PARTIALS (plain stores, no atomics): outpart[by][2N] = {sum[N], sumsq[N]}.
// BN input stats reduced from inpart[128][2K] in the preamble.
// tile 32x64, KC=32, 256 threads, micro-tile 2x4; grid (N/64, 128)
template<int BN_IN>
__global__ __launch_bounds__(256) void k_gemm(const float* __restrict__ A, const float* __restrict__ W,
                                              const float* __restrict__ bias,
                                              const float* __restrict__ inpart,
                                              const float* __restrict__ gam, const float* __restrict__ bet,
                                              float* __restrict__ C, float* __restrict__ outpart,
                                              int K, int N){
    __shared__ float As[32][33];
    __shared__ float Ws[32][64];
    __shared__ float bnsc[256], bnsh[256];
    __shared__ float red[16][16][8];

    const int tid = threadIdx.x;
    const int n0  = blockIdx.x * 64;
    const int b0  = blockIdx.y * 32;

    if (BN_IN){
        for (int k = tid; k < K; k += 256){
            float s = 0.f, ss = 0.f;
            #pragma unroll 4
            for (int p = 0; p < GEMM_GB; ++p){
                s  += inpart[(size_t)p*(2*K) + k];
                ss += inpart[(size_t)p*(2*K) + K + k];
            }
            float m  = s  * (1.0f/BATCH);
            float v  = ss * (1.0f/BATCH) - m*m;
            float rs = rsqrtf(v + BN_EPS);
            float sc = gam[k]*rs;
            bnsc[k] = sc;
            bnsh[k] = fmaf(-m, sc, bet[k]);
        }
        __syncthreads();
    }

    const int nt = tid & 15;            // 16 col-groups * 4 cols
    const int bt = tid >> 4;            // 16 row-groups * 2 rows
    float acc[2][4];
    #pragma unroll
    for (int r = 0; r < 2; ++r)
        #pragma unroll
        for (int j = 0; j < 4; ++j) acc[r][j] = 0.f;

    for (int kc = 0; kc < K; kc += 32){
        #pragma unroll
        for (int idx = tid; idx < 32*32; idx += 256){
            int r = idx >> 5, k = idx & 31;
            float a = A[(size_t)(b0 + r)*K + kc + k];
            if (BN_IN) a = fmaf(a, bnsc[kc + k], bnsh[kc + k]);
            As[r][k] = a;
        }
        #pragma unroll
        for (int idx = tid; idx < 32*64; idx += 256){
            int k = idx >> 6, n = idx & 63;
            Ws[k][n] = W[(size_t)(kc + k)*N + n0 + n];
        }
        __syncthreads();
        #pragma unroll
        for (int k = 0; k < 32; ++k){
            float4 w = *reinterpret_cast<const float4*>(&Ws[k][nt*4]);
            float a0 = As[bt*2+0][k], a1 = As[bt*2+1][k];
            acc[0][0] = fmaf(a0, w.x, acc[0][0]); acc[0][1] = fmaf(a0, w.y, acc[0][1]);
            acc[0][2] = fmaf(a0, w.z, acc[0][2]); acc[0][3] = fmaf(a0, w.w, acc[0][3]);
            acc[1][0] = fmaf(a1, w.x, acc[1][0]); acc[1][1] = fmaf(a1, w.y, acc[1][1]);
            acc[1][2] = fmaf(a1, w.z, acc[1][2]); acc[1][3] = fmaf(a1, w.w, acc[1][3]);
        }
        __syncthreads();
    }

    float bs[4];
    #pragma unroll
    for (int j = 0; j < 4; ++j) bs[j] = bias[n0 + nt*4 + j];
    float lsum[4] = {0,0,0,0}, lsq[4] = {0,0,0,0};
    #pragma unroll
    for (int r = 0; r < 2; ++r){
        int brow = b0 + bt*2 + r;
        float vv[4];
        #pragma unroll
        for (int j = 0; j < 4; ++j){
            float v1 = acc[r][j] + bs[j];
            v1 = fmaxf(v1, 0.f);
            vv[j] = v1;
            lsum[j] += v1;
            lsq[j]  = fmaf(v1, v1, lsq[j]);
        }
        *reinterpret_cast<float4*>(&C[(size_t)brow*N + n0 + nt*4]) =
            make_float4(vv[0], vv[1], vv[2], vv[3]);
    }
    #pragma unroll
    for (int j = 0; j < 4; ++j){ red[bt][nt][j] = lsum[j]; red[bt][nt][4+j] = lsq[j]; }
    __syncthreads();
    for (int s = 8; s > 0; s >>= 1){
        if (bt < s){
            #pragma unroll
            for (int f = 0; f < 8; ++f) red[bt][nt][f] += red[bt+s][nt][f];
        }
        __syncthreads();
    }
    if (bt == 0){
        float* op = outpart + (size_t)blockIdx.y*(2*N);
        #pragma unroll
        for (int j = 0; j < 4; ++j){
            op[n0 + nt*4 + j]     = red[0][nt][j];
            op[N + n0 + nt*4 + j] = red[0][nt][4+j];
        }
    }
}

// out = BN(A3) @ w4 + b4   (BN stats reduced from part3[128][128])
__global__ __launch_bounds__(256) void k_final(const float* __restrict__ A3, const float* __restrict__ part3,
                                               const float* __restrict__ g3, const float* __restrict__ be3,
                                               const float* __restrict__ w4, const float* __restrict__ b4,
                                               float* __restrict__ out){
    __shared__ float sc[64], sh[64];
    int t = threadIdx.x;
    if (t < 64){
        float s = 0.f, ss = 0.f;
        #pragma unroll 4
        for (int p = 0; p < GEMM_GB; ++p){
            s  += part3[(size_t)p*128 + t];
            ss += part3[(size_t)p*128 + 64 + t];
        }
        float m  = s  * (1.0f/BATCH);
        float v  = ss * (1.0f/BATCH) - m*m;
        float rs = rsqrtf(v + BN_EPS);
        float g  = g3[t]*rs;
        sc[t] = g * w4[t];
        sh[t] = fmaf(-m, g, be3[t]) * w4[t];
    }
    __syncthreads();
    int row = blockIdx.x*256 + t;
    const float* a = A3 + (size_t)row*64;
    float acc = b4[0];
    #pragma unroll
    for (int k = 0; k < 64; ++k){
        acc = fmaf(a[k], sc[k], acc);
        acc += sh[k];
    }
    out[row] = acc;
}

extern "C" void kernel_launch(void* const* d_in, const int* in_sizes, int n_in,
                              void* d_out, int out_size, void* d_ws, size_t ws_size,
                              hipStream_t stream){
    const float* x     = (const float*)d_in[0];
    const float* fs    = (const float*)d_in[1];
    const float* grids = (const float*)d_in[2];
    const float* w1 = (const float*)d_in[3];  const float* b1 = (const float*)d_in[4];
    const float* g1 = (const float*)d_in[5];  const float* be1= (const float*)d_in[6];
    const float* w2 = (const float*)d_in[7];  const float* b2 = (const float*)d_in[8];
    const float* g2 = (const float*)d_in[9];  const float* be2= (const float*)d_in[10];
    const float* w3 = (const float*)d_in[11]; const float* b3 = (const float*)d_in[12];
    const float* g3 = (const float*)d_in[13]; const float* be3= (const float*)d_in[14];
    const float* w4 = (const float*)d_in[15]; const float* b4 = (const float*)d_in[16];
    float* out = (float*)d_out;

    char* ws = (char*)d_ws;
    float* mmp    = (float*)(ws + O_MMP);
    float* p1     = (float*)(ws + O_P1);
    float* p2     = (float*)(ws + O_P2);
    float* p3     = (float*)(ws + O_P3);
    unsigned* STb = (unsigned*)(ws + O_STB);
    float* h      = (float*)(ws + O_H);
    float* A1     = (float*)(ws + O_A1);
    float* A2     = (float*)(ws + O_A2);
    float* A3     = (float*)(ws + O_A3);

    k_prep<<<272, 256, 0, stream>>>(x, fs, grids, mmp, STb);
    k_gather<<<2048, 128, 0, stream>>>(x, mmp, STb, h);
    k_gemm<0><<<dim3(4, 128), 256, 0, stream>>>(h,  w1, b1, nullptr, nullptr, nullptr, A1, p1, 128, 256);
    k_gemm<1><<<dim3(2, 128), 256, 0, stream>>>(A1, w2, b2, p1, g1, be1,            A2, p2, 256, 128);
    k_gemm<1><<<dim3(1, 128), 256, 0, stream>>>(A2, w3, b3, p2, g2, be2,            A3, p3, 128, 64);
    k_final<<<16, 256, 0, stream>>>(A3, p3, g3, be3, w4, b4, out);
}

// Round 13
// 128.067 us; speedup vs baseline: 1.6770x; 1.0971x over previous
//
#include <hip/hip_runtime.h>
#include <hip/hip_fp16.h>

#define BATCH 4096
#define IN_DIM 256
#define GRID_N 64
#define HID 128
#define GEMM_GB 128            // b-blocks per layer (BATCH/32)
constexpr float BN_EPS = 1e-5f;

// ---------------- workspace layout (bytes) ----------------
static const size_t O_MMP  = 0;                      // 16 partials * 512 f = 32768 B
static const size_t O_P1   = 32768;                  // stats partials L1: 128*512 f = 256 KB
static const size_t O_P2   = O_P1 + 262144;          // 128*256 f = 128 KB
static const size_t O_P3   = O_P2 + 131072;          // 128*128 f = 64 KB
static const size_t O_STB  = O_P3 + 65536;           // packed fp16 table: 256*65*128 u32
static const size_t O_H    = O_STB + (size_t)256*65*128*4;
static const size_t O_A1   = O_H  + (size_t)4096*128*4;
static const size_t O_A2   = O_A1 + (size_t)4096*256*4;
static const size_t O_A3   = O_A2 + (size_t)4096*128*4;

// blocks 0..15: minmax partials (256 rows each).
// blocks 16..271: packed prefix tables STb[i][K][h] = pack(fp16(S1), fp16(-S2)), i = bid-16
__global__ __launch_bounds__(256) void k_prep(const float* __restrict__ x, const float* __restrict__ fs,
                                              const float* __restrict__ grids,
                                              float* __restrict__ mmp, unsigned* __restrict__ STb){
    const int tid = threadIdx.x;
    const int bid = blockIdx.x;
    if (bid < 16){
        const float* xp = x + (size_t)bid*256*IN_DIM + tid;
        float mn = 1e30f, mx = -1e30f;
        #pragma unroll 8
        for (int r = 0; r < 256; ++r){
            float v = xp[(size_t)r*IN_DIM];
            mn = fminf(mn, v); mx = fmaxf(mx, v);
        }
        mmp[(size_t)bid*512 + tid]       = mn;
        mmp[(size_t)bid*512 + 256 + tid] = mx;
        return;
    }
    if (tid >= 128) return;
    const int i = bid - 16;             // 0..255
    const int h = tid;                  // 0..127
    const float* f0 = fs + ((size_t)(0*IN_DIM + i)*GRID_N)*HID + h;
    const float* f1 = fs + ((size_t)(1*IN_DIM + i)*GRID_N)*HID + h;
    const float* f2 = fs + ((size_t)(2*IN_DIM + i)*GRID_N)*HID + h;
    unsigned* st = STb + (size_t)i*65*HID + h;
    float acc1 = 0.f, acc2 = 0.f;
    st[0] = 0u;
    #pragma unroll 4
    for (int k = 0; k < 64; ++k){
        float fv = f0[(size_t)k*HID] + f1[(size_t)k*HID] + f2[(size_t)k*HID];
        float g  = grids[k];            // row 0 (identical across depth)
        acc1 += fv;
        acc2  = fmaf(g, fv, acc2);
        __half2 hh = __halves2half2(__float2half_rn(acc1), __float2half_rn(-acc2));
        st[(size_t)(k+1)*HID] = *reinterpret_cast<unsigned*>(&hh);
    }
}

// h[b,:] = sum_i ( z*S1[i,K0,:] - S2[i,K0,:] )  [fp16 packed table]
// 2 waves/block, one batch row per wave. Half-wave dual-row gather:
// lanes 0..31 walk i in [0,128), lanes 32..63 walk i in [128,256);
// each lane loads uint4 = 4 h-values; halves combined via __shfl.
__global__ __launch_bounds__(128) void k_gather(const float* __restrict__ x, const float* __restrict__ mmp,
                                                const unsigned* __restrict__ STb, float* __restrict__ h){
    __shared__ float s_zmin[256], s_inv[256];
    __shared__ float2 pre[2][256];      // (z, byte-offset bitcast) per (row_local, i)
    const int tid = threadIdx.x;
    const int b0  = blockIdx.x * 2;

    // reduce 16 min/max partials (L2-hot)
    for (int f = tid; f < 256; f += 128){
        float mn = 1e30f, mx = -1e30f;
        #pragma unroll
        for (int p = 0; p < 16; ++p){
            mn = fminf(mn, mmp[(size_t)p*512 + f]);
            mx = fmaxf(mx, mmp[(size_t)p*512 + 256 + f]);
        }
        s_zmin[f] = mn;
        s_inv[f]  = 1.0f / (mx - mn + 1e-6f);
    }
    __syncthreads();

    // precompute z and table-row byte offsets (coalesced x reads)
    for (int idx = tid; idx < 2*256; idx += 128){
        int bl = idx >> 8, i = idx & 255;
        float z = (x[(size_t)(b0 + bl)*IN_DIM + i] - s_zmin[i]) * s_inv[i];
        int K0 = (int)(z * 63.0f) + 1;
        K0 = max(1, min(63, K0));
        unsigned off = ((unsigned)(i*65 + K0)) << 9;    // row stride = 128 u32 = 512 B
        pre[bl][i] = make_float2(z, __uint_as_float(off));
    }
    __syncthreads();

    const int w  = tid >> 6;            // wave id = local row
    const int l  = tid & 63;
    const int hl = l & 31;              // h-group lane: covers h = 4*hl .. 4*hl+3
    const int hi = l >> 5;              // 0: i in [0,128), 1: i in [128,256)
    const char* base = (const char*)STb + (size_t)hl * 16;
    const float2* pp = &pre[w][hi * 128];
    float acc0 = 0.f, acc1 = 0.f, acc2 = 0.f, acc3 = 0.f;
    #pragma unroll 8
    for (int ii = 0; ii < 128; ++ii){
        float2 p = pp[ii];              // uniform per half-wave -> broadcast
        uint4 u = *reinterpret_cast<const uint4*>(base + __float_as_uint(p.y));
        float2 fa = __half22float2(*reinterpret_cast<__half2*>(&u.x));
        float2 fb = __half22float2(*reinterpret_cast<__half2*>(&u.y));
        float2 fc = __half22float2(*reinterpret_cast<__half2*>(&u.z));
        float2 fd = __half22float2(*reinterpret_cast<__half2*>(&u.w));
        acc0 += fmaf(p.x, fa.x, fa.y);
        acc1 += fmaf(p.x, fb.x, fb.y);
        acc2 += fmaf(p.x, fc.x, fc.y);
        acc3 += fmaf(p.x, fd.x, fd.y);
    }
    // combine i-halves: low lanes pull high lanes' partials
    acc0 += __shfl(acc0, hl + 32);
    acc1 += __shfl(acc1, hl + 32);
    acc2 += __shfl(acc2, hl + 32);
    acc3 += __shfl(acc3, hl + 32);
    if (hi == 0){
        *reinterpret_cast<float4*>(&h[(size_t)(b0 + w)*HID + 4*hl]) =
            make_float4(acc0, acc1, acc2, acc3);
    }
}

// fp32 GEMM: C = relu(bn?(A) @ W + bias); per-column stats stored as PER-BLOCK
// PARTIALS (plain stores, no atomics): outpart[by][2N] = {sum[N], sumsq[N]}.
// BN input stats reduced from inpart[128][2K] in the preamble.
// tile 32x64, KC=32, 256 threads, micro-tile 2x4; grid (N/64, 128)
template<int BN_IN>
__global__ __launch_bounds__(256) void k_gemm(const float* __restrict__ A, const float* __restrict__ W,
                                              const float* __restrict__ bias,
                                              const float* __restrict__ inpart,
                                              const float* __restrict__ gam, const float* __restrict__ bet,
                                              float* __restrict__ C, float* __restrict__ outpart,
                                              int K, int N){
    __shared__ float As[32][33];
    __shared__ float Ws[32][64];
    __shared__ float bnsc[256], bnsh[256];
    __shared__ float red[16][16][8];

    const int tid = threadIdx.x;
    const int n0  = blockIdx.x * 64;
    const int b0  = blockIdx.y * 32;

    if (BN_IN){
        for (int k = tid; k < K; k += 256){
            float s = 0.f, ss = 0.f;
            #pragma unroll 4
            for (int p = 0; p < GEMM_GB; ++p){
                s  += inpart[(size_t)p*(2*K) + k];
                ss += inpart[(size_t)p*(2*K) + K + k];
            }
            float m  = s  * (1.0f/BATCH);
            float v  = ss * (1.0f/BATCH) - m*m;
            float rs = rsqrtf(v + BN_EPS);
            float sc = gam[k]*rs;
            bnsc[k] = sc;
            bnsh[k] = fmaf(-m, sc, bet[k]);
        }
        __syncthreads();
    }

    const int nt = tid & 15;            // 16 col-groups * 4 cols
    const int bt = tid >> 4;            // 16 row-groups * 2 rows
    float acc[2][4];
    #pragma unroll
    for (int r = 0; r < 2; ++r)
        #pragma unroll
        for (int j = 0; j < 4; ++j) acc[r][j] = 0.f;

    for (int kc = 0; kc < K; kc += 32){
        #pragma unroll
        for (int idx = tid; idx < 32*32; idx += 256){
            int r = idx >> 5, k = idx & 31;
            float a = A[(size_t)(b0 + r)*K + kc + k];
            if (BN_IN) a = fmaf(a, bnsc[kc + k], bnsh[kc + k]);
            As[r][k] = a;
        }
        #pragma unroll
        for (int idx = tid; idx < 32*64; idx += 256){
            int k = idx >> 6, n = idx & 63;
            Ws[k][n] = W[(size_t)(kc + k)*N + n0 + n];
        }
        __syncthreads();
        #pragma unroll
        for (int k = 0; k < 32; ++k){
            float4 w = *reinterpret_cast<const float4*>(&Ws[k][nt*4]);
            float a0 = As[bt*2+0][k], a1 = As[bt*2+1][k];
            acc[0][0] = fmaf(a0, w.x, acc[0][0]); acc[0][1] = fmaf(a0, w.y, acc[0][1]);
            acc[0][2] = fmaf(a0, w.z, acc[0][2]); acc[0][3] = fmaf(a0, w.w, acc[0][3]);
            acc[1][0] = fmaf(a1, w.x, acc[1][0]); acc[1][1] = fmaf(a1, w.y, acc[1][1]);
            acc[1][2] = fmaf(a1, w.z, acc[1][2]); acc[1][3] = fmaf(a1, w.w, acc[1][3]);
        }
        __syncthreads();
    }

    float bs[4];
    #pragma unroll
    for (int j = 0; j < 4; ++j) bs[j] = bias[n0 + nt*4 + j];
    float lsum[4] = {0,0,0,0}, lsq[4] = {0,0,0,0};
    #pragma unroll
    for (int r = 0; r < 2; ++r){
        int brow = b0 + bt*2 + r;
        float vv[4];
        #pragma unroll
        for (int j = 0; j < 4; ++j){
            float v1 = acc[r][j] + bs[j];
            v1 = fmaxf(v1, 0.f);
            vv[j] = v1;
            lsum[j] += v1;
            lsq[j]  = fmaf(v1, v1, lsq[j]);
        }
        *reinterpret_cast<float4*>(&C[(size_t)brow*N + n0 + nt*4]) =
            make_float4(vv[0], vv[1], vv[2], vv[3]);
    }
    #pragma unroll
    for (int j = 0; j < 4; ++j){ red[bt][nt][j] = lsum[j]; red[bt][nt][4+j] = lsq[j]; }
    __syncthreads();
    for (int s = 8; s > 0; s >>= 1){
        if (bt < s){
            #pragma unroll
            for (int f = 0; f < 8; ++f) red[bt][nt][f] += red[bt+s][nt][f];
        }
        __syncthreads();
    }
    if (bt == 0){
        float* op = outpart + (size_t)blockIdx.y*(2*N);
        #pragma unroll
        for (int j = 0; j < 4; ++j){
            op[n0 + nt*4 + j]     = red[0][nt][j];
            op[N + n0 + nt*4 + j] = red[0][nt][4+j];
        }
    }
}

// out = BN(A3) @ w4 + b4   (BN stats reduced from part3[128][128])
__global__ __launch_bounds__(256) void k_final(const float* __restrict__ A3, const float* __restrict__ part3,
                                               const float* __restrict__ g3, const float* __restrict__ be3,
                                               const float* __restrict__ w4, const float* __restrict__ b4,
                                               float* __restrict__ out){
    __shared__ float sc[64], sh[64];
    int t = threadIdx.x;
    if (t < 64){
        float s = 0.f, ss = 0.f;
        #pragma unroll 4
        for (int p = 0; p < GEMM_GB; ++p){
            s  += part3[(size_t)p*128 + t];
            ss += part3[(size_t)p*128 + 64 + t];
        }
        float m  = s  * (1.0f/BATCH);
        float v  = ss * (1.0f/BATCH) - m*m;
        float rs = rsqrtf(v + BN_EPS);
        float g  = g3[t]*rs;
        sc[t] = g * w4[t];
        sh[t] = fmaf(-m, g, be3[t]) * w4[t];
    }
    __syncthreads();
    int row = blockIdx.x*256 + t;
    const float* a = A3 + (size_t)row*64;
    float acc = b4[0];
    #pragma unroll
    for (int k = 0; k < 64; ++k){
        acc = fmaf(a[k], sc[k], acc);
        acc += sh[k];
    }
    out[row] = acc;
}

extern "C" void kernel_launch(void* const* d_in, const int* in_sizes, int n_in,
                              void* d_out, int out_size, void* d_ws, size_t ws_size,
                              hipStream_t stream){
    const float* x     = (const float*)d_in[0];
    const float* fs    = (const float*)d_in[1];
    const float* grids = (const float*)d_in[2];
    const float* w1 = (const float*)d_in[3];  const float* b1 = (const float*)d_in[4];
    const float* g1 = (const float*)d_in[5];  const float* be1= (const float*)d_in[6];
    const float* w2 = (const float*)d_in[7];  const float* b2 = (const float*)d_in[8];
    const float* g2 = (const float*)d_in[9];  const float* be2= (const float*)d_in[10];
    const float* w3 = (const float*)d_in[11]; const float* b3 = (const float*)d_in[12];
    const float* g3 = (const float*)d_in[13]; const float* be3= (const float*)d_in[14];
    const float* w4 = (const float*)d_in[15]; const float* b4 = (const float*)d_in[16];
    float* out = (float*)d_out;

    char* ws = (char*)d_ws;
    float* mmp    = (float*)(ws + O_MMP);
    float* p1     = (float*)(ws + O_P1);
    float* p2     = (float*)(ws + O_P2);
    float* p3     = (float*)(ws + O_P3);
    unsigned* STb = (unsigned*)(ws + O_STB);
    float* h      = (float*)(ws + O_H);
    float* A1     = (float*)(ws + O_A1);
    float* A2     = (float*)(ws + O_A2);
    float* A3     = (float*)(ws + O_A3);

    k_prep<<<272, 256, 0, stream>>>(x, fs, grids, mmp, STb);
    k_gather<<<2048, 128, 0, stream>>>(x, mmp, STb, h);
    k_gemm<0><<<dim3(4, 128), 256, 0, stream>>>(h,  w1, b1, nullptr, nullptr, nullptr, A1, p1, 128, 256);
    k_gemm<1><<<dim3(2, 128), 256, 0, stream>>>(A1, w2, b2, p1, g1, be1,            A2, p2, 256, 128);
    k_gemm<1><<<dim3(1, 128), 256, 0, stream>>>(A2, w3, b3, p2, g2, be2,            A3, p3, 128, 64);
    k_final<<<16, 256, 0, stream>>>(A3, p3, g3, be3, w4, b4, out);
}

// Round 15
// 127.690 us; speedup vs baseline: 1.6819x; 1.0030x over previous
//
#include <hip/hip_runtime.h>
#include <hip/hip_fp16.h>

#define BATCH 4096
#define IN_DIM 256
#define GRID_N 64
#define HID 128
#define GEMM_GB 128            // b-blocks per layer (BATCH/32)
constexpr float BN_EPS = 1e-5f;

typedef _Float16 h2 __attribute__((ext_vector_type(2)));
__device__ __forceinline__ h2 as_h2(unsigned u){ union {unsigned x; h2 h;} c; c.x = u; return c.h; }

// ---------------- workspace layout (bytes) ----------------
static const size_t O_MMP  = 0;                      // 16 partials * 512 f = 32768 B
static const size_t O_P1   = 32768;                  // stats partials L1: 128*512 f = 256 KB
static const size_t O_P2   = O_P1 + 262144;          // 128*256 f = 128 KB
static const size_t O_P3   = O_P2 + 131072;          // 128*128 f = 64 KB
static const size_t O_STB  = O_P3 + 65536;           // packed fp16 table: 256*65*128 u32
static const size_t O_H    = O_STB + (size_t)256*65*128*4;
static const size_t O_A1   = O_H  + (size_t)4096*128*4;
static const size_t O_A2   = O_A1 + (size_t)4096*256*4;
static const size_t O_A3   = O_A2 + (size_t)4096*128*4;

// blocks 0..15: minmax partials (256 rows each).
// blocks 16..143: packed prefix tables, 2 i-columns per block (all 256 threads active)
//   STb[i][K][h] = pack(fp16(S1), fp16(-S2)), i = (bid-16)*2 + (tid>>7), h = tid&127
__global__ __launch_bounds__(256) void k_prep(const float* __restrict__ x, const float* __restrict__ fs,
                                              const float* __restrict__ grids,
                                              float* __restrict__ mmp, unsigned* __restrict__ STb){
    const int tid = threadIdx.x;
    const int bid = blockIdx.x;
    if (bid < 16){
        const float* xp = x + (size_t)bid*256*IN_DIM + tid;
        float mn = 1e30f, mx = -1e30f;
        #pragma unroll 8
        for (int r = 0; r < 256; ++r){
            float v = xp[(size_t)r*IN_DIM];
            mn = fminf(mn, v); mx = fmaxf(mx, v);
        }
        mmp[(size_t)bid*512 + tid]       = mn;
        mmp[(size_t)bid*512 + 256 + tid] = mx;
        return;
    }
    const int i = (bid - 16)*2 + (tid >> 7);  // 0..255
    const int h = tid & 127;                  // 0..127
    const float* f0 = fs + ((size_t)(0*IN_DIM + i)*GRID_N)*HID + h;
    const float* f1 = fs + ((size_t)(1*IN_DIM + i)*GRID_N)*HID + h;
    const float* f2 = fs + ((size_t)(2*IN_DIM + i)*GRID_N)*HID + h;
    unsigned* st = STb + (size_t)i*65*HID + h;
    float acc1 = 0.f, acc2 = 0.f;
    st[0] = 0u;
    #pragma unroll 4
    for (int k = 0; k < 64; ++k){
        float fv = f0[(size_t)k*HID] + f1[(size_t)k*HID] + f2[(size_t)k*HID];
        float g  = grids[k];            // row 0 (identical across depth)
        acc1 += fv;
        acc2  = fmaf(g, fv, acc2);
        __half2 hh = __halves2half2(__float2half_rn(acc1), __float2half_rn(-acc2));
        st[(size_t)(k+1)*HID] = *reinterpret_cast<unsigned*>(&hh);
    }
}

// h[b,:] = sum_i ( z*S1[i,K0,:] - S2[i,K0,:] )  [fp16 packed table, v_dot2_f32_f16]
// 2 waves/block, one batch row per wave. Half-wave dual-row gather:
// lanes 0..31 walk i in [0,128), lanes 32..63 walk i in [128,256);
// each lane loads uint4 = 4 h-values; acc += dot2((z,1),(S1,-S2)).
__global__ __launch_bounds__(128) void k_gather(const float* __restrict__ x, const float* __restrict__ mmp,
                                                const unsigned* __restrict__ STb, float* __restrict__ h){
    __shared__ float s_zmin[256], s_inv[256];
    __shared__ uint2 pre[2][256];       // (half2(z,1) bits, byte-offset) per (row_local, i)
    const int tid = threadIdx.x;
    const int b0  = blockIdx.x * 2;

    // reduce 16 min/max partials (L2-hot)
    for (int f = tid; f < 256; f += 128){
        float mn = 1e30f, mx = -1e30f;
        #pragma unroll
        for (int p = 0; p < 16; ++p){
            mn = fminf(mn, mmp[(size_t)p*512 + f]);
            mx = fmaxf(mx, mmp[(size_t)p*512 + 256 + f]);
        }
        s_zmin[f] = mn;
        s_inv[f]  = 1.0f / (mx - mn + 1e-6f);
    }
    __syncthreads();

    // precompute packed (z,1) and table-row byte offsets (coalesced x reads)
    for (int idx = tid; idx < 2*256; idx += 128){
        int bl = idx >> 8, i = idx & 255;
        float z = (x[(size_t)(b0 + bl)*IN_DIM + i] - s_zmin[i]) * s_inv[i];
        int K0 = (int)(z * 63.0f) + 1;
        K0 = max(1, min(63, K0));
        unsigned off = ((unsigned)(i*65 + K0)) << 9;    // row stride = 128 u32 = 512 B
        __half2 zh = __halves2half2(__float2half_rn(z), __float2half_rn(1.0f));
        pre[bl][i] = make_uint2(*reinterpret_cast<unsigned*>(&zh), off);
    }
    __syncthreads();

    const int w  = tid >> 6;            // wave id = local row
    const int l  = tid & 63;
    const int hl = l & 31;              // h-group lane: covers h = 4*hl .. 4*hl+3
    const int hi = l >> 5;              // 0: i in [0,128), 1: i in [128,256)
    const char* base = (const char*)STb + (size_t)hl * 16;
    const uint2* pp = &pre[w][hi * 128];
    float acc0 = 0.f, acc1 = 0.f, acc2 = 0.f, acc3 = 0.f;
    #pragma unroll 8
    for (int ii = 0; ii < 128; ++ii){
        uint2 p = pp[ii];               // uniform per half-wave -> broadcast
        uint4 u = *reinterpret_cast<const uint4*>(base + p.y);
        h2 zz = as_h2(p.x);
        acc0 = __builtin_amdgcn_fdot2(zz, as_h2(u.x), acc0, false);
        acc1 = __builtin_amdgcn_fdot2(zz, as_h2(u.y), acc1, false);
        acc2 = __builtin_amdgcn_fdot2(zz, as_h2(u.z), acc2, false);
        acc3 = __builtin_amdgcn_fdot2(zz, as_h2(u.w), acc3, false);
    }
    // combine i-halves: low lanes pull high lanes' partials
    acc0 += __shfl(acc0, hl + 32);
    acc1 += __shfl(acc1, hl + 32);
    acc2 += __shfl(acc2, hl + 32);
    acc3 += __shfl(acc3, hl + 32);
    if (hi == 0){
        *reinterpret_cast<float4*>(&h[(size_t)(b0 + w)*HID + 4*hl]) =
            make_float4(acc0, acc1, acc2, acc3);
    }
}

// fp32 GEMM: C = relu(bn?(A) @ W + bias); per-column stats stored as PER-BLOCK
// PARTIALS (plain stores, no atomics): outpart[by][2N] = {sum[N], sumsq[N]}.
// BN input stats reduced from inpart[128][2K] in the preamble.
// tile 32x64, KC=32, 256 threads, micro-tile 2x4; grid (N/64, 128)
template<int BN_IN>
__global__ __launch_bounds__(256) void k_gemm(const float* __restrict__ A, const float* __restrict__ W,
                                              const float* __restrict__ bias,
                                              const float* __restrict__ inpart,
                                              const float* __restrict__ gam, const float* __restrict__ bet,
                                              float* __restrict__ C, float* __restrict__ outpart,
                                              int K, int N){
    __shared__ float As[32][33];
    __shared__ float Ws[32][64];
    __shared__ float bnsc[256], bnsh[256];
    __shared__ float red[16][16][8];

    const int tid = threadIdx.x;
    const int n0  = blockIdx.x * 64;
    const int b0  = blockIdx.y * 32;

    if (BN_IN){
        for (int k = tid; k < K; k += 256){
            float s = 0.f, ss = 0.f;
            #pragma unroll 4
            for (int p = 0; p < GEMM_GB; ++p){
                s  += inpart[(size_t)p*(2*K) + k];
                ss += inpart[(size_t)p*(2*K) + K + k];
            }
            float m  = s  * (1.0f/BATCH);
            float v  = ss * (1.0f/BATCH) - m*m;
            float rs = rsqrtf(v + BN_EPS);
            float sc = gam[k]*rs;
            bnsc[k] = sc;
            bnsh[k] = fmaf(-m, sc, bet[k]);
        }
        __syncthreads();
    }

    const int nt = tid & 15;            // 16 col-groups * 4 cols
    const int bt = tid >> 4;            // 16 row-groups * 2 rows
    float acc[2][4];
    #pragma unroll
    for (int r = 0; r < 2; ++r)
        #pragma unroll
        for (int j = 0; j < 4; ++j) acc[r][j] = 0.f;

    for (int kc = 0; kc < K; kc += 32){
        #pragma unroll
        for (int idx = tid; idx < 32*32; idx += 256){
            int r = idx >> 5, k = idx & 31;
            float a = A[(size_t)(b0 + r)*K + kc + k];
            if (BN_IN) a = fmaf(a, bnsc[kc + k], bnsh[kc + k]);
            As[r][k] = a;
        }
        #pragma unroll
        for (int idx = tid; idx < 32*64; idx += 256){
            int k = idx >> 6, n = idx & 63;
            Ws[k][n] = W[(size_t)(kc + k)*N + n0 + n];
        }
        __syncthreads();
        #pragma unroll
        for (int k = 0; k < 32; ++k){
            float4 w = *reinterpret_cast<const float4*>(&Ws[k][nt*4]);
            float a0 = As[bt*2+0][k], a1 = As[bt*2+1][k];
            acc[0][0] = fmaf(a0, w.x, acc[0][0]); acc[0][1] = fmaf(a0, w.y, acc[0][1]);
            acc[0][2] = fmaf(a0, w.z, acc[0][2]); acc[0][3] = fmaf(a0, w.w, acc[0][3]);
            acc[1][0] = fmaf(a1, w.x, acc[1][0]); acc[1][1] = fmaf(a1, w.y, acc[1][1]);
            acc[1][2] = fmaf(a1, w.z, acc[1][2]); acc[1][3] = fmaf(a1, w.w, acc[1][3]);
        }
        __syncthreads();
    }

    float bs[4];
    #pragma unroll
    for (int j = 0; j < 4; ++j) bs[j] = bias[n0 + nt*4 + j];
    float lsum[4] = {0,0,0,0}, lsq[4] = {0,0,0,0};
    #pragma unroll
    for (int r = 0; r < 2; ++r){
        int brow = b0 + bt*2 + r;
        float vv[4];
        #pragma unroll
        for (int j = 0; j < 4; ++j){
            float v1 = acc[r][j] + bs[j];
            v1 = fmaxf(v1, 0.f);
            vv[j] = v1;
            lsum[j] += v1;
            lsq[j]  = fmaf(v1, v1, lsq[j]);
        }
        *reinterpret_cast<float4*>(&C[(size_t)brow*N + n0 + nt*4]) =
            make_float4(vv[0], vv[1], vv[2], vv[3]);
    }
    #pragma unroll
    for (int j = 0; j < 4; ++j){ red[bt][nt][j] = lsum[j]; red[bt][nt][4+j] = lsq[j]; }
    __syncthreads();
    for (int s = 8; s > 0; s >>= 1){
        if (bt < s){
            #pragma unroll
            for (int f = 0; f < 8; ++f) red[bt][nt][f] += red[bt+s][nt][f];
        }
        __syncthreads();
    }
    if (bt == 0){
        float* op = outpart + (size_t)blockIdx.y*(2*N);
        #pragma unroll
        for (int j = 0; j < 4; ++j){
            op[n0 + nt*4 + j]     = red[0][nt][j];
            op[N + n0 + nt*4 + j] = red[0][nt][4+j];
        }
    }
}

// out = BN(A3) @ w4 + b4   (BN stats reduced from part3[128][128])
__global__ __launch_bounds__(256) void k_final(const float* __restrict__ A3, const float* __restrict__ part3,
                                               const float* __restrict__ g3, const float* __restrict__ be3,
                                               const float* __restrict__ w4, const float* __restrict__ b4,
                                               float* __restrict__ out){
    __shared__ float sc[64], sh[64];
    int t = threadIdx.x;
    if (t < 64){
        float s = 0.f, ss = 0.f;
        #pragma unroll 4
        for (int p = 0; p < GEMM_GB; ++p){
            s  += part3[(size_t)p*128 + t];
            ss += part3[(size_t)p*128 + 64 + t];
        }
        float m  = s  * (1.0f/BATCH);
        float v  = ss * (1.0f/BATCH) - m*m;
        float rs = rsqrtf(v + BN_EPS);
        float g  = g3[t]*rs;
        sc[t] = g * w4[t];
        sh[t] = fmaf(-m, g, be3[t]) * w4[t];
    }
    __syncthreads();
    int row = blockIdx.x*256 + t;
    const float* a = A3 + (size_t)row*64;
    float acc = b4[0];
    #pragma unroll
    for (int k = 0; k < 64; ++k){
        acc = fmaf(a[k], sc[k], acc);
        acc += sh[k];
    }
    out[row] = acc;
}

extern "C" void kernel_launch(void* const* d_in, const int* in_sizes, int n_in,
                              void* d_out, int out_size, void* d_ws, size_t ws_size,
                              hipStream_t stream){
    const float* x     = (const float*)d_in[0];
    const float* fs    = (const float*)d_in[1];
    const float* grids = (const float*)d_in[2];
    const float* w1 = (const float*)d_in[3];  const float* b1 = (const float*)d_in[4];
    const float* g1 = (const float*)d_in[5];  const float* be1= (const float*)d_in[6];
    const float* w2 = (const float*)d_in[7];  const float* b2 = (const float*)d_in[8];
    const float* g2 = (const float*)d_in[9];  const float* be2= (const float*)d_in[10];
    const float* w3 = (const float*)d_in[11]; const float* b3 = (const float*)d_in[12];
    const float* g3 = (const float*)d_in[13]; const float* be3= (const float*)d_in[14];
    const float* w4 = (const float*)d_in[15]; const float* b4 = (const float*)d_in[16];
    float* out = (float*)d_out;

    char* ws = (char*)d_ws;
    float* mmp    = (float*)(ws + O_MMP);
    float* p1     = (float*)(ws + O_P1);
    float* p2     = (float*)(ws + O_P2);
    float* p3     = (float*)(ws + O_P3);
    unsigned* STb = (unsigned*)(ws + O_STB);
    float* h      = (float*)(ws + O_H);
    float* A1     = (float*)(ws + O_A1);
    float* A2     = (float*)(ws + O_A2);
    float* A3     = (float*)(ws + O_A3);

    k_prep<<<144, 256, 0, stream>>>(x, fs, grids, mmp, STb);
    k_gather<<<2048, 128, 0, stream>>>(x, mmp, STb, h);
    k_gemm<0><<<dim3(4, 128), 256, 0, stream>>>(h,  w1, b1, nullptr, nullptr, nullptr, A1, p1, 128, 256);
    k_gemm<1><<<dim3(2, 128), 256, 0, stream>>>(A1, w2, b2, p1, g1, be1,            A2, p2, 256, 128);
    k_gemm<1><<<dim3(1, 128), 256, 0, stream>>>(A2, w3, b3, p2, g2, be2,            A3, p3, 128, 64);
    k_final<<<16, 256, 0, stream>>>(A3, p3, g3, be3, w4, b4, out);
}

// Round 16
// 119.441 us; speedup vs baseline: 1.7981x; 1.0691x over previous
//
#include <hip/hip_runtime.h>
#include <hip/hip_fp16.h>

#define BATCH 4096
#define IN_DIM 256
#define GRID_N 64
#define HID 128
#define GEMM_GB 128            // b-blocks per layer (BATCH/32)
constexpr float BN_EPS = 1e-5f;

typedef _Float16 h2 __attribute__((ext_vector_type(2)));
__device__ __forceinline__ h2 as_h2(unsigned u){ union {unsigned x; h2 h;} c; c.x = u; return c.h; }

// ---------------- workspace layout (bytes) ----------------
static const size_t O_MMP  = 0;                      // 16 partials * 512 f = 32768 B
static const size_t O_P1   = 32768;                  // stats partials L1: 128*512 f = 256 KB
static const size_t O_P2   = O_P1 + 262144;          // 128*256 f = 128 KB
static const size_t O_P3   = O_P2 + 131072;          // 128*128 f = 64 KB
static const size_t O_SS1  = O_P3 + 65536;           // reduced stats L1: 512 f
static const size_t O_SS2  = O_SS1 + 2048;           // 256 f
static const size_t O_SS3  = O_SS2 + 1024;           // 128 f
static const size_t O_STB  = O_SS3 + 1024;           // packed fp16 table: 256*65*128 u32
static const size_t O_H    = O_STB + (size_t)256*65*128*4;
static const size_t O_A1   = O_H  + (size_t)4096*128*4;
static const size_t O_A2   = O_A1 + (size_t)4096*256*4;
static const size_t O_A3   = O_A2 + (size_t)4096*128*4;

// blocks 0..15: minmax partials (256 rows each).
// blocks 16..143: packed prefix tables, 2 i-columns per block (all 256 threads active)
//   STb[i][K][h] = pack(fp16(S1), fp16(-S2)), i = (bid-16)*2 + (tid>>7), h = tid&127
__global__ __launch_bounds__(256) void k_prep(const float* __restrict__ x, const float* __restrict__ fs,
                                              const float* __restrict__ grids,
                                              float* __restrict__ mmp, unsigned* __restrict__ STb){
    const int tid = threadIdx.x;
    const int bid = blockIdx.x;
    if (bid < 16){
        const float* xp = x + (size_t)bid*256*IN_DIM + tid;
        float mn = 1e30f, mx = -1e30f;
        #pragma unroll 8
        for (int r = 0; r < 256; ++r){
            float v = xp[(size_t)r*IN_DIM];
            mn = fminf(mn, v); mx = fmaxf(mx, v);
        }
        mmp[(size_t)bid*512 + tid]       = mn;
        mmp[(size_t)bid*512 + 256 + tid] = mx;
        return;
    }
    const int i = (bid - 16)*2 + (tid >> 7);  // 0..255
    const int h = tid & 127;                  // 0..127
    const float* f0 = fs + ((size_t)(0*IN_DIM + i)*GRID_N)*HID + h;
    const float* f1 = fs + ((size_t)(1*IN_DIM + i)*GRID_N)*HID + h;
    const float* f2 = fs + ((size_t)(2*IN_DIM + i)*GRID_N)*HID + h;
    unsigned* st = STb + (size_t)i*65*HID + h;
    float acc1 = 0.f, acc2 = 0.f;
    st[0] = 0u;
    #pragma unroll 4
    for (int k = 0; k < 64; ++k){
        float fv = f0[(size_t)k*HID] + f1[(size_t)k*HID] + f2[(size_t)k*HID];
        float g  = grids[k];            // row 0 (identical across depth)
        acc1 += fv;
        acc2  = fmaf(g, fv, acc2);
        __half2 hh = __halves2half2(__float2half_rn(acc1), __float2half_rn(-acc2));
        st[(size_t)(k+1)*HID] = *reinterpret_cast<unsigned*>(&hh);
    }
}

// h[b,:] = sum_i ( z*S1[i,K0,:] - S2[i,K0,:] )  [fp16 packed table, v_dot2_f32_f16]
__global__ __launch_bounds__(128) void k_gather(const float* __restrict__ x, const float* __restrict__ mmp,
                                                const unsigned* __restrict__ STb, float* __restrict__ h){
    __shared__ float s_zmin[256], s_inv[256];
    __shared__ uint2 pre[2][256];       // (half2(z,1) bits, byte-offset) per (row_local, i)
    const int tid = threadIdx.x;
    const int b0  = blockIdx.x * 2;

    for (int f = tid; f < 256; f += 128){
        float mn = 1e30f, mx = -1e30f;
        #pragma unroll
        for (int p = 0; p < 16; ++p){
            mn = fminf(mn, mmp[(size_t)p*512 + f]);
            mx = fmaxf(mx, mmp[(size_t)p*512 + 256 + f]);
        }
        s_zmin[f] = mn;
        s_inv[f]  = 1.0f / (mx - mn + 1e-6f);
    }
    __syncthreads();

    for (int idx = tid; idx < 2*256; idx += 128){
        int bl = idx >> 8, i = idx & 255;
        float z = (x[(size_t)(b0 + bl)*IN_DIM + i] - s_zmin[i]) * s_inv[i];
        int K0 = (int)(z * 63.0f) + 1;
        K0 = max(1, min(63, K0));
        unsigned off = ((unsigned)(i*65 + K0)) << 9;    // row stride = 128 u32 = 512 B
        __half2 zh = __halves2half2(__float2half_rn(z), __float2half_rn(1.0f));
        pre[bl][i] = make_uint2(*reinterpret_cast<unsigned*>(&zh), off);
    }
    __syncthreads();

    const int w  = tid >> 6;            // wave id = local row
    const int l  = tid & 63;
    const int hl = l & 31;              // h-group lane: covers h = 4*hl .. 4*hl+3
    const int hi = l >> 5;              // 0: i in [0,128), 1: i in [128,256)
    const char* base = (const char*)STb + (size_t)hl * 16;
    const uint2* pp = &pre[w][hi * 128];
    float acc0 = 0.f, acc1 = 0.f, acc2 = 0.f, acc3 = 0.f;
    #pragma unroll 8
    for (int ii = 0; ii < 128; ++ii){
        uint2 p = pp[ii];               // uniform per half-wave -> broadcast
        uint4 u = *reinterpret_cast<const uint4*>(base + p.y);
        h2 zz = as_h2(p.x);
        acc0 = __builtin_amdgcn_fdot2(zz, as_h2(u.x), acc0, false);
        acc1 = __builtin_amdgcn_fdot2(zz, as_h2(u.y), acc1, false);
        acc2 = __builtin_amdgcn_fdot2(zz, as_h2(u.z), acc2, false);
        acc3 = __builtin_amdgcn_fdot2(zz, as_h2(u.w), acc3, false);
    }
    acc0 += __shfl(acc0, hl + 32);
    acc1 += __shfl(acc1, hl + 32);
    acc2 += __shfl(acc2, hl + 32);
    acc3 += __shfl(acc3, hl + 32);
    if (hi == 0){
        *reinterpret_cast<float4*>(&h[(size_t)(b0 + w)*HID + 4*hl]) =
            make_float4(acc0, acc1, acc2, acc3);
    }
}

// reduce per-block stats partials ONCE: stats[j] = sum_p part[p][j], j < twoN
__global__ __launch_bounds__(256) void k_stats(const float* __restrict__ part, float* __restrict__ stats,
                                               int twoN){
    int j = blockIdx.x*256 + threadIdx.x;
    if (j >= twoN) return;
    float s = 0.f;
    #pragma unroll 8
    for (int p = 0; p < GEMM_GB; ++p) s += part[(size_t)p*twoN + j];
    stats[j] = s;
}

// fp32 GEMM: C = relu(bn?(A) @ W + bias); per-column stats -> per-block partials
// (plain stores). BN input from pre-reduced stats[2K] (tiny).
// tile 32x64, KC=32, 256 threads, micro-tile 2x4; grid (N/64, 128)
template<int BN_IN>
__global__ __launch_bounds__(256) void k_gemm(const float* __restrict__ A, const float* __restrict__ W,
                                              const float* __restrict__ bias,
                                              const float* __restrict__ instats,
                                              const float* __restrict__ gam, const float* __restrict__ bet,
                                              float* __restrict__ C, float* __restrict__ outpart,
                                              int K, int N){
    __shared__ float As[32][33];
    __shared__ float Ws[32][64];
    __shared__ float bnsc[256], bnsh[256];
    __shared__ float red[16][16][8];

    const int tid = threadIdx.x;
    const int n0  = blockIdx.x * 64;
    const int b0  = blockIdx.y * 32;

    if (BN_IN){
        for (int k = tid; k < K; k += 256){
            float m  = instats[k]     * (1.0f/BATCH);
            float v  = instats[K + k] * (1.0f/BATCH) - m*m;
            float rs = rsqrtf(v + BN_EPS);
            float sc = gam[k]*rs;
            bnsc[k] = sc;
            bnsh[k] = fmaf(-m, sc, bet[k]);
        }
        __syncthreads();
    }

    const int nt = tid & 15;            // 16 col-groups * 4 cols
    const int bt = tid >> 4;            // 16 row-groups * 2 rows
    float acc[2][4];
    #pragma unroll
    for (int r = 0; r < 2; ++r)
        #pragma unroll
        for (int j = 0; j < 4; ++j) acc[r][j] = 0.f;

    for (int kc = 0; kc < K; kc += 32){
        #pragma unroll
        for (int idx = tid; idx < 32*32; idx += 256){
            int r = idx >> 5, k = idx & 31;
            float a = A[(size_t)(b0 + r)*K + kc + k];
            if (BN_IN) a = fmaf(a, bnsc[kc + k], bnsh[kc + k]);
            As[r][k] = a;
        }
        #pragma unroll
        for (int idx = tid; idx < 32*64; idx += 256){
            int k = idx >> 6, n = idx & 63;
            Ws[k][n] = W[(size_t)(kc + k)*N + n0 + n];
        }
        __syncthreads();
        #pragma unroll
        for (int k = 0; k < 32; ++k){
            float4 w = *reinterpret_cast<const float4*>(&Ws[k][nt*4]);
            float a0 = As[bt*2+0][k], a1 = As[bt*2+1][k];
            acc[0][0] = fmaf(a0, w.x, acc[0][0]); acc[0][1] = fmaf(a0, w.y, acc[0][1]);
            acc[0][2] = fmaf(a0, w.z, acc[0][2]); acc[0][3] = fmaf(a0, w.w, acc[0][3]);
            acc[1][0] = fmaf(a1, w.x, acc[1][0]); acc[1][1] = fmaf(a1, w.y, acc[1][1]);
            acc[1][2] = fmaf(a1, w.z, acc[1][2]); acc[1][3] = fmaf(a1, w.w, acc[1][3]);
        }
        __syncthreads();
    }

    float bs[4];
    #pragma unroll
    for (int j = 0; j < 4; ++j) bs[j] = bias[n0 + nt*4 + j];
    float lsum[4] = {0,0,0,0}, lsq[4] = {0,0,0,0};
    #pragma unroll
    for (int r = 0; r < 2; ++r){
        int brow = b0 + bt*2 + r;
        float vv[4];
        #pragma unroll
        for (int j = 0; j < 4; ++j){
            float v1 = acc[r][j] + bs[j];
            v1 = fmaxf(v1, 0.f);
            vv[j] = v1;
            lsum[j] += v1;
            lsq[j]  = fmaf(v1, v1, lsq[j]);
        }
        *reinterpret_cast<float4*>(&C[(size_t)brow*N + n0 + nt*4]) =
            make_float4(vv[0], vv[1], vv[2], vv[3]);
    }
    #pragma unroll
    for (int j = 0; j < 4; ++j){ red[bt][nt][j] = lsum[j]; red[bt][nt][4+j] = lsq[j]; }
    __syncthreads();
    for (int s = 8; s > 0; s >>= 1){
        if (bt < s){
            #pragma unroll
            for (int f = 0; f < 8; ++f) red[bt][nt][f] += red[bt+s][nt][f];
        }
        __syncthreads();
    }
    if (bt == 0){
        float* op = outpart + (size_t)blockIdx.y*(2*N);
        #pragma unroll
        for (int j = 0; j < 4; ++j){
            op[n0 + nt*4 + j]     = red[0][nt][j];
            op[N + n0 + nt*4 + j] = red[0][nt][4+j];
        }
    }
}

// out = BN(A3) @ w4 + b4   (BN stats from pre-reduced ss3[128])
__global__ __launch_bounds__(256) void k_final(const float* __restrict__ A3, const float* __restrict__ ss3,
                                               const float* __restrict__ g3, const float* __restrict__ be3,
                                               const float* __restrict__ w4, const float* __restrict__ b4,
                                               float* __restrict__ out){
    __shared__ float sc[64], sh[64];
    int t = threadIdx.x;
    if (t < 64){
        float m  = ss3[t]      * (1.0f/BATCH);
        float v  = ss3[64 + t] * (1.0f/BATCH) - m*m;
        float rs = rsqrtf(v + BN_EPS);
        float g  = g3[t]*rs;
        sc[t] = g * w4[t];
        sh[t] = fmaf(-m, g, be3[t]) * w4[t];
    }
    __syncthreads();
    int row = blockIdx.x*256 + t;
    const float* a = A3 + (size_t)row*64;
    float acc = b4[0];
    #pragma unroll
    for (int k = 0; k < 64; ++k){
        acc = fmaf(a[k], sc[k], acc);
        acc += sh[k];
    }
    out[row] = acc;
}

extern "C" void kernel_launch(void* const* d_in, const int* in_sizes, int n_in,
                              void* d_out, int out_size, void* d_ws, size_t ws_size,
                              hipStream_t stream){
    const float* x     = (const float*)d_in[0];
    const float* fs    = (const float*)d_in[1];
    const float* grids = (const float*)d_in[2];
    const float* w1 = (const float*)d_in[3];  const float* b1 = (const float*)d_in[4];
    const float* g1 = (const float*)d_in[5];  const float* be1= (const float*)d_in[6];
    const float* w2 = (const float*)d_in[7];  const float* b2 = (const float*)d_in[8];
    const float* g2 = (const float*)d_in[9];  const float* be2= (const float*)d_in[10];
    const float* w3 = (const float*)d_in[11]; const float* b3 = (const float*)d_in[12];
    const float* g3 = (const float*)d_in[13]; const float* be3= (const float*)d_in[14];
    const float* w4 = (const float*)d_in[15]; const float* b4 = (const float*)d_in[16];
    float* out = (float*)d_out;

    char* ws = (char*)d_ws;
    float* mmp    = (float*)(ws + O_MMP);
    float* p1     = (float*)(ws + O_P1);
    float* p2     = (float*)(ws + O_P2);
    float* p3     = (float*)(ws + O_P3);
    float* ss1    = (float*)(ws + O_SS1);
    float* ss2    = (float*)(ws + O_SS2);
    float* ss3    = (float*)(ws + O_SS3);
    unsigned* STb = (unsigned*)(ws + O_STB);
    float* h      = (float*)(ws + O_H);
    float* A1     = (float*)(ws + O_A1);
    float* A2     = (float*)(ws + O_A2);
    float* A3     = (float*)(ws + O_A3);

    k_prep<<<144, 256, 0, stream>>>(x, fs, grids, mmp, STb);
    k_gather<<<2048, 128, 0, stream>>>(x, mmp, STb, h);
    k_gemm<0><<<dim3(4, 128), 256, 0, stream>>>(h,  w1, b1, nullptr, nullptr, nullptr, A1, p1, 128, 256);
    k_stats<<<2, 256, 0, stream>>>(p1, ss1, 512);
    k_gemm<1><<<dim3(2, 128), 256, 0, stream>>>(A1, w2, b2, ss1, g1, be1,            A2, p2, 256, 128);
    k_stats<<<1, 256, 0, stream>>>(p2, ss2, 256);
    k_gemm<1><<<dim3(1, 128), 256, 0, stream>>>(A2, w3, b3, ss2, g2, be2,            A3, p3, 128, 64);
    k_stats<<<1, 256, 0, stream>>>(p3, ss3, 128);
    k_final<<<16, 256, 0, stream>>>(A3, ss3, g3, be3, w4, b4, out);
}